// Round 1
// baseline (1354.516 us; speedup 1.0000x reference)
//
#include <hip/hip_runtime.h>
#include <hip/hip_fp16.h>
#include <cstdint>
#include <cstddef>

#define BATCH 8
#define TT 8192
#define HD 256
#define RTOT (BATCH * TT)   // 65536
#define CHUNK 32
#define NCHUNK (TT / CHUNK) // 256

typedef __attribute__((ext_vector_type(4))) float    f32x4;
typedef __attribute__((ext_vector_type(8))) _Float16 f16x8;
typedef __attribute__((ext_vector_type(4))) _Float16 f16x4;

// ---------------------------------------------------------------------------
// Detect storage format of the 'start' flags buffer (65536 elements):
// mode 1 = int32 (bytes at %4!=0 all zero), mode 2 = float32 (0.0f/1.0f),
// mode 0 = bool bytes. All-zero buffer -> mode 1, semantics identical.
// ---------------------------------------------------------------------------
__global__ void detect_start_mode(const unsigned char* __restrict__ s,
                                  int* __restrict__ mode) {
  __shared__ int bad_int, bad_f32;
  if (threadIdx.x == 0) { bad_int = 0; bad_f32 = 0; }
  __syncthreads();
  int bi = 0, bf = 0;
  for (int i = threadIdx.x; i < BATCH * TT; i += blockDim.x) {
    const unsigned char v = s[i];
    const int m = i & 3;
    if (m != 0 && v != 0) bi = 1;
    if (m == 0 || m == 1) { if (v != 0) bf = 1; }
    else if (m == 2)      { if (v != 0 && v != 0x80) bf = 1; }
    else                  { if (v != 0 && v != 0x3f) bf = 1; }
  }
  if (bi) atomicOr(&bad_int, 1);
  if (bf) atomicOr(&bad_f32, 1);
  __syncthreads();
  if (threadIdx.x == 0) *mode = (!bad_int) ? 1 : (!bad_f32 ? 2 : 0);
}

// ---------------------------------------------------------------------------
// fp32 GEMM: C[r,n] = act(sum_k A[r,k] * W[n,k] + bias[n])
// A: [RTOT,256], W: [256,256] row-major (row n = output n), act: 0 none,
// 1 leaky_relu(0.01). BM=BN=64, BK=32, 256 threads, 4x4 per thread.
// ---------------------------------------------------------------------------
__global__ __launch_bounds__(256) void gemm_f32(
    const float* __restrict__ A, const float* __restrict__ W,
    const float* __restrict__ bias, float* __restrict__ C, const int act) {
  __shared__ float As[32][64];
  __shared__ float Ws[32][64];
  const int tid  = threadIdx.x;
  const int bm   = blockIdx.x * 64;
  const int bn   = blockIdx.y * 64;
  const int lrow = tid >> 2;         // 0..63
  const int lk   = (tid & 3) * 8;    // 0,8,16,24
  const int m0   = (tid & 15) * 4;
  const int n0   = (tid >> 4) * 4;
  float acc[4][4] = {{0.f}};
  for (int k0 = 0; k0 < HD; k0 += 32) {
    const float4 a0 = *(const float4*)&A[(size_t)(bm + lrow) * HD + k0 + lk];
    const float4 a1 = *(const float4*)&A[(size_t)(bm + lrow) * HD + k0 + lk + 4];
    const float4 w0 = *(const float4*)&W[(size_t)(bn + lrow) * HD + k0 + lk];
    const float4 w1 = *(const float4*)&W[(size_t)(bn + lrow) * HD + k0 + lk + 4];
    __syncthreads();
    As[lk + 0][lrow] = a0.x; As[lk + 1][lrow] = a0.y;
    As[lk + 2][lrow] = a0.z; As[lk + 3][lrow] = a0.w;
    As[lk + 4][lrow] = a1.x; As[lk + 5][lrow] = a1.y;
    As[lk + 6][lrow] = a1.z; As[lk + 7][lrow] = a1.w;
    Ws[lk + 0][lrow] = w0.x; Ws[lk + 1][lrow] = w0.y;
    Ws[lk + 2][lrow] = w0.z; Ws[lk + 3][lrow] = w0.w;
    Ws[lk + 4][lrow] = w1.x; Ws[lk + 5][lrow] = w1.y;
    Ws[lk + 6][lrow] = w1.z; Ws[lk + 7][lrow] = w1.w;
    __syncthreads();
#pragma unroll
    for (int kk = 0; kk < 32; kk++) {
      const float4 av = *(const float4*)&As[kk][m0];
      const float4 wv = *(const float4*)&Ws[kk][n0];
      const float am[4] = {av.x, av.y, av.z, av.w};
      const float wn[4] = {wv.x, wv.y, wv.z, wv.w};
#pragma unroll
      for (int i = 0; i < 4; i++)
#pragma unroll
        for (int j = 0; j < 4; j++)
          acc[i][j] = fmaf(am[i], wn[j], acc[i][j]);
    }
  }
#pragma unroll
  for (int i = 0; i < 4; i++) {
    float4 o;
#pragma unroll
    for (int j = 0; j < 4; j++) {
      float v = acc[i][j] + bias[bn + n0 + j];
      if (act == 1) v = (v > 0.f) ? v : 0.01f * v;
      (&o.x)[j] = v;
    }
    *(float4*)&C[(size_t)(bm + m0 + i) * HD + bn + n0] = o;
  }
}

// ---------------------------------------------------------------------------
// MGU scan, chunked time-parallel. One WG (8 waves, 512 thr) per time chunk,
// all 8 batches in lockstep as MFMA N-dim (cols 0..7 real, 8..15 pad).
// Weights fp16 in registers (MFMA A-frags); carry h kept fp32 in LDS.
// Each WG scans back to the last reset <= chunk start (exact recompute).
// ---------------------------------------------------------------------------
__global__ __launch_bounds__(512, 2) void scan_mgu(
    const float* __restrict__ xf, const float* __restrict__ xh,
    const void* __restrict__ startp, const int* __restrict__ modep,
    const float* __restrict__ h0l,
    const float* __restrict__ Ufp, const float* __restrict__ Uhp,
    float* __restrict__ z, float* __restrict__ hfin) {
  const int tid  = threadIdx.x;
  const int wave = tid >> 6;      // 0..7
  const int lane = tid & 63;
  const int bcol = lane & 15;     // MFMA col = batch (real < 8)
  const int krow = lane >> 4;     // 0..3
  const int mode = *modep;
  const int t0   = blockIdx.x * CHUNK;
  const int tend = t0 + CHUNK;

  __shared__ __align__(16) float    h32[16][260];  // padded strides: no bank conflicts
  __shared__ __align__(16) _Float16 h16[16][264];
  __shared__ __align__(16) _Float16 g16[16][264];
  __shared__ int rb[8];

  auto flag = [&](int b, int t) -> int {
    const int idx = b * TT + t;
    if (mode == 1) return ((const int*)startp)[idx] != 0;
    if (mode == 2) return ((const float*)startp)[idx] != 0.0f;
    return ((const uint8_t*)startp)[idx] != 0;
  };

  // Load Uf/Uh fragments: wave owns n-tiles {2*wave, 2*wave+1}.
  // A-frag (16x16x32): lane holds U[ntile*16 + (lane&15)][kc*32 + (lane>>4)*8 + e]
  f16x8 auf[2][8], auh[2][8];
#pragma unroll
  for (int tile = 0; tile < 2; tile++) {
    const int nrow = (wave * 2 + tile) * 16 + bcol;
#pragma unroll
    for (int kc = 0; kc < 8; kc++) {
      const int kb = kc * 32 + krow * 8;
      f16x8 vf, vh;
#pragma unroll
      for (int e = 0; e < 8; e++) {
        vf[e] = (_Float16)Ufp[nrow * HD + kb + e];
        vh[e] = (_Float16)Uhp[nrow * HD + kb + e];
      }
      auf[tile][kc] = vf;
      auh[tile][kc] = vh;
    }
  }

  // Find last reset <= t0 per batch (backward windows of 64).
  if (tid < 8) rb[tid] = -1;
  __syncthreads();
  for (int base = t0; base >= 0; base -= 64) {
    const int sb = tid >> 6;
    const int st = base - (tid & 63);
    if (st >= 0 && rb[sb] < 0 && flag(sb, st)) atomicMax(&rb[sb], st);
    __syncthreads();
    bool all_found = true;
#pragma unroll
    for (int b2 = 0; b2 < 8; b2++) all_found = all_found && (rb[b2] >= 0);
    if (all_found) break;
    __syncthreads();
  }
  int tb = TT;
#pragma unroll
  for (int b2 = 0; b2 < 8; b2++) {
    int r = rb[b2];
    if (r < 0) r = 0;               // no reset found: replay from t=0 with h0
    tb = min(tb, r);
  }

  // Initialize carry at t = tb.
  {
    const int b = tid >> 6;         // 0..7
    const int n = (tid & 63) * 4;
    float4 hv = make_float4(0.f, 0.f, 0.f, 0.f);
    if (rb[b] < 0) hv = *(const float4*)&h0l[b * HD + n];
    if (flag(b, tb)) hv = make_float4(0.f, 0.f, 0.f, 0.f);
    *(float4*)&h32[b][n] = hv;
    f16x4 h4;
    h4[0] = (_Float16)hv.x; h4[1] = (_Float16)hv.y;
    h4[2] = (_Float16)hv.z; h4[3] = (_Float16)hv.w;
    *(f16x4*)&h16[b][n] = h4;
  }
  __syncthreads();

  const int bb = (bcol < 8) ? bcol : 7;  // clamp pad lanes for address safety
  for (int t = tb; t < tend; t++) {
    // C-operand preload: xf/xh for this step (D layout: n=(lane>>4)*4+r, b=lane&15)
    f32x4 cf[2], ch[2];
    float4 hcur[2];
#pragma unroll
    for (int tile = 0; tile < 2; tile++) {
      const int nb = (wave * 2 + tile) * 16 + krow * 4;
      const size_t ro = ((size_t)bb * TT + t) * HD + nb;
      const float4 xfv = *(const float4*)&xf[ro];
      const float4 xhv = *(const float4*)&xh[ro];
      cf[tile] = (f32x4){xfv.x, xfv.y, xfv.z, xfv.w};
      ch[tile] = (f32x4){xhv.x, xhv.y, xhv.z, xhv.w};
    }
    // matvec1: pre_f = Uf . h + xf
#pragma unroll
    for (int kc = 0; kc < 8; kc++) {
      const f16x8 bv = *(const f16x8*)&h16[bcol][kc * 32 + krow * 8];
      cf[0] = __builtin_amdgcn_mfma_f32_16x16x32_f16(auf[0][kc], bv, cf[0], 0, 0, 0);
      cf[1] = __builtin_amdgcn_mfma_f32_16x16x32_f16(auf[1][kc], bv, cf[1], 0, 0, 0);
    }
    // f = sigmoid(pre_f); g = f*h (fp32 h from LDS), rounded to fp16 for matvec2
    f32x4 fv[2];
#pragma unroll
    for (int tile = 0; tile < 2; tile++) {
      const int nb = (wave * 2 + tile) * 16 + krow * 4;
      const float4 h4 = *(const float4*)&h32[bcol][nb];
      hcur[tile] = h4;
      f16x4 g4;
#pragma unroll
      for (int r = 0; r < 4; r++) {
        const float fr = 1.f / (1.f + __expf(-cf[tile][r]));
        fv[tile][r] = fr;
        g4[r] = (_Float16)(fr * (&h4.x)[r]);
      }
      *(f16x4*)&g16[bcol][nb] = g4;
    }
    __syncthreads();
    // matvec2: pre_h = Uh . (f*h) + xh
#pragma unroll
    for (int kc = 0; kc < 8; kc++) {
      const f16x8 bv = *(const f16x8*)&g16[bcol][kc * 32 + krow * 8];
      ch[0] = __builtin_amdgcn_mfma_f32_16x16x32_f16(auh[0][kc], bv, ch[0], 0, 0, 0);
      ch[1] = __builtin_amdgcn_mfma_f32_16x16x32_f16(auh[1][kc], bv, ch[1], 0, 0, 0);
    }
    // update; fold next step's reset into the stored carry
    const int stn = (t + 1 < TT) ? flag(bb, t + 1) : 0;
#pragma unroll
    for (int tile = 0; tile < 2; tile++) {
      const int nb = (wave * 2 + tile) * 16 + krow * 4;
      float4 hn;
#pragma unroll
      for (int r = 0; r < 4; r++) {
        const float e2 = __expf(2.f * ch[tile][r]);
        const float hh = 1.f - 2.f / (e2 + 1.f);   // tanh
        const float fr = fv[tile][r];
        (&hn.x)[r] = (1.f - fr) * (&hcur[tile].x)[r] + fr * hh;
      }
      if (bcol < 8) {
        if (t >= t0) *(float4*)&z[((size_t)bcol * TT + t) * HD + nb] = hn;
        if (t == TT - 1) *(float4*)&hfin[bcol * HD + nb] = hn;
      }
      float4 hst = hn;
      if (stn) hst = make_float4(0.f, 0.f, 0.f, 0.f);
      *(float4*)&h32[bcol][nb] = hst;
      f16x4 h4s;
      h4s[0] = (_Float16)hst.x; h4s[1] = (_Float16)hst.y;
      h4s[2] = (_Float16)hst.z; h4s[3] = (_Float16)hst.w;
      *(f16x4*)&h16[bcol][nb] = h4s;
    }
    __syncthreads();
  }
}

// ---------------------------------------------------------------------------
extern "C" void kernel_launch(void* const* d_in, const int* in_sizes, int n_in,
                              void* d_out, int out_size, void* d_ws, size_t ws_size,
                              hipStream_t stream) {
  const float* emb    = (const float*)d_in[0];
  const void*  startp = d_in[1];
  const float* h0     = (const float*)d_in[2];
  const float* min_w  = (const float*)d_in[3];
  const float* min_b  = (const float*)d_in[4];
  const float* mout_w = (const float*)d_in[5];
  const float* mout_b = (const float*)d_in[6];
  const float* Wf_w   = (const float*)d_in[7];
  const float* Wf_b   = (const float*)d_in[8];
  const float* Wh_w   = (const float*)d_in[9];
  const float* Wh_b   = (const float*)d_in[10];
  const float* Uf_w   = (const float*)d_in[11];
  const float* Uh_w   = (const float*)d_in[12];
  const float* ff_w   = (const float*)d_in[13];
  const float* ff_b   = (const float*)d_in[14];

  float* out = (float*)d_out;
  char*  ws  = (char*)d_ws;
  int*   mode = (int*)ws;
  const size_t SZ = (size_t)RTOT * HD * sizeof(float);  // 64 MB
  float* buf0 = (float*)(ws + 1024);
  float* buf1 = (float*)(ws + 1024 + SZ);
  float* buf2 = (float*)(ws + 1024 + 2 * SZ);
  float* hfin = out + (size_t)RTOT * HD;                // h_final [L,B,H]
  const size_t WO = (size_t)HD * HD;

  detect_start_mode<<<1, 256, 0, stream>>>((const unsigned char*)startp, mode);

  const dim3 gg(RTOT / 64, HD / 64);
  // x = emb @ min_w^T + min_b
  gemm_f32<<<gg, 256, 0, stream>>>(emb, min_w, min_b, buf0, 0);
  // ---- layer 0 ----
  gemm_f32<<<gg, 256, 0, stream>>>(buf0, Wf_w, Wf_b, buf1, 0);
  gemm_f32<<<gg, 256, 0, stream>>>(buf0, Wh_w, Wh_b, buf2, 0);
  scan_mgu<<<NCHUNK, 512, 0, stream>>>(buf1, buf2, startp, mode, h0,
                                       Uf_w, Uh_w, buf0, hfin);
  gemm_f32<<<gg, 256, 0, stream>>>(buf0, ff_w, ff_b, buf1, 1);
  // ---- layer 1 ----
  gemm_f32<<<gg, 256, 0, stream>>>(buf1, Wf_w + WO, Wf_b + HD, buf2, 0);
  gemm_f32<<<gg, 256, 0, stream>>>(buf1, Wh_w + WO, Wh_b + HD, buf0, 0);
  scan_mgu<<<NCHUNK, 512, 0, stream>>>(buf2, buf0, startp, mode, h0 + BATCH * HD,
                                       Uf_w + WO, Uh_w + WO, buf1, hfin + BATCH * HD);
  gemm_f32<<<gg, 256, 0, stream>>>(buf1, ff_w + WO, ff_b + HD, buf2, 1);
  // out = x @ mout_w^T + mout_b
  gemm_f32<<<gg, 256, 0, stream>>>(buf2, mout_w, mout_b, out, 0);
}

// Round 2
// 588.030 us; speedup vs baseline: 2.3035x; 2.3035x over previous
//
#include <hip/hip_runtime.h>
#include <hip/hip_fp16.h>
#include <cstdint>
#include <cstddef>

#define BATCH 8
#define TT 8192
#define HD 256
#define RTOT (BATCH * TT)   // 65536
#define CHUNK 32
#define NCHUNK (TT / CHUNK) // 256

typedef __attribute__((ext_vector_type(4))) float    f32x4;
typedef __attribute__((ext_vector_type(8))) _Float16 f16x8;
typedef __attribute__((ext_vector_type(4))) _Float16 f16x4;

typedef __attribute__((address_space(1))) const void gvoid_t;
typedef __attribute__((address_space(3))) void lvoid_t;

__device__ __forceinline__ void gl_lds16(const void* g, void* l) {
  __builtin_amdgcn_global_load_lds((gvoid_t*)g, (lvoid_t*)l, 16, 0, 0);
}

// ---------------------------------------------------------------------------
// Detect storage format of the 'start' flags buffer.
// ---------------------------------------------------------------------------
__global__ void detect_start_mode(const unsigned char* __restrict__ s,
                                  int* __restrict__ mode) {
  __shared__ int bad_int, bad_f32;
  if (threadIdx.x == 0) { bad_int = 0; bad_f32 = 0; }
  __syncthreads();
  int bi = 0, bf = 0;
  for (int i = threadIdx.x; i < BATCH * TT; i += blockDim.x) {
    const unsigned char v = s[i];
    const int m = i & 3;
    if (m != 0 && v != 0) bi = 1;
    if (m == 0 || m == 1) { if (v != 0) bf = 1; }
    else if (m == 2)      { if (v != 0 && v != 0x80) bf = 1; }
    else                  { if (v != 0 && v != 0x3f) bf = 1; }
  }
  if (bi) atomicOr(&bad_int, 1);
  if (bf) atomicOr(&bad_f32, 1);
  __syncthreads();
  if (threadIdx.x == 0) *mode = (!bad_int) ? 1 : (!bad_f32 ? 2 : 0);
}

// ---------------------------------------------------------------------------
// f32 -> f16 conversion, vectorized (8 elems/thread).
// ---------------------------------------------------------------------------
__global__ void conv_f16(const float* __restrict__ in, _Float16* __restrict__ out,
                         const int n) {
  const int i = (blockIdx.x * blockDim.x + threadIdx.x) * 8;
  if (i + 7 >= n) return;
  const float4 a = *(const float4*)&in[i];
  const float4 b = *(const float4*)&in[i + 4];
  f16x8 v;
  v[0] = (_Float16)a.x; v[1] = (_Float16)a.y; v[2] = (_Float16)a.z; v[3] = (_Float16)a.w;
  v[4] = (_Float16)b.x; v[5] = (_Float16)b.y; v[6] = (_Float16)b.z; v[7] = (_Float16)b.w;
  *(f16x8*)&out[i] = v;
}

// 8 weight matrices (65536 f32 each) -> contiguous f16 segments.
__global__ void conv_w8(const float* p0, const float* p1, const float* p2,
                        const float* p3, const float* p4, const float* p5,
                        const float* p6, const float* p7,
                        _Float16* __restrict__ out) {
  const int seg = blockIdx.y;
  const float* p;
  switch (seg) {
    case 0: p = p0; break; case 1: p = p1; break;
    case 2: p = p2; break; case 3: p = p3; break;
    case 4: p = p4; break; case 5: p = p5; break;
    case 6: p = p6; break; default: p = p7; break;
  }
  const int i = (blockIdx.x * blockDim.x + threadIdx.x) * 8;
  const float4 a = *(const float4*)&p[i];
  const float4 b = *(const float4*)&p[i + 4];
  f16x8 v;
  v[0] = (_Float16)a.x; v[1] = (_Float16)a.y; v[2] = (_Float16)a.z; v[3] = (_Float16)a.w;
  v[4] = (_Float16)b.x; v[5] = (_Float16)b.y; v[6] = (_Float16)b.z; v[7] = (_Float16)b.w;
  *(f16x8*)&out[(size_t)seg * 65536 + i] = v;
}

// ---------------------------------------------------------------------------
// fp16 MFMA GEMM: C[r,n] = act(sum_k A[r,k]*W[n,k] + bias[n]).
// A [RTOT,256] f16, W [256,256] f16 row-major (row n). 128x128 tile, BK=32,
// 256 thr (4 waves, 2x2), global_load_lds staging, f32 accumulate.
// C16 path: LDS-repack epilogue, coalesced f16 stores. C32 path: direct f32.
// ---------------------------------------------------------------------------
__global__ __launch_bounds__(256, 4) void gemm_h(
    const _Float16* __restrict__ A, const _Float16* __restrict__ W,
    const float* __restrict__ bias, _Float16* __restrict__ C16,
    float* __restrict__ C32, const int act) {
  __shared__ __align__(16) char smem[34816];
  _Float16* As = (_Float16*)smem;            // [128][32] (8 KB)
  _Float16* Ws = (_Float16*)(smem + 8192);   // [128][32] (8 KB)
  _Float16* EP = (_Float16*)smem;            // [128][136] epilogue reuse

  const int tid  = threadIdx.x;
  const int wave = tid >> 6, lane = tid & 63;
  const int wm = wave >> 1, wn = wave & 1;
  const int bm = blockIdx.x * 128, bn = blockIdx.y * 128;
  const int lrow  = tid >> 2;         // 0..63 staging row
  const int lcol8 = (tid & 3) * 8;    // staging k offset
  const int fr = lane & 15;           // frag row/col
  const int fq = lane >> 4;           // 0..3

  f32x4 acc[4][4];
#pragma unroll
  for (int i = 0; i < 4; i++)
#pragma unroll
    for (int j = 0; j < 4; j++) acc[i][j] = (f32x4){0.f, 0.f, 0.f, 0.f};

  float bv[4];
#pragma unroll
  for (int ni = 0; ni < 4; ni++) bv[ni] = bias[bn + wn * 64 + ni * 16 + fr];

  for (int k0 = 0; k0 < HD; k0 += 32) {
    __syncthreads();  // previous iteration's frag reads done
#pragma unroll
    for (int is = 0; is < 2; is++) {
      gl_lds16(&A[(size_t)(bm + is * 64 + lrow) * HD + k0 + lcol8],
               smem + wave * 1024 + is * 4096);
      gl_lds16(&W[(size_t)(bn + is * 64 + lrow) * HD + k0 + lcol8],
               smem + 8192 + wave * 1024 + is * 4096);
    }
    asm volatile("s_waitcnt vmcnt(0)" ::: "memory");
    __syncthreads();
    f16x8 af[4], bf[4];
#pragma unroll
    for (int mi = 0; mi < 4; mi++)
      af[mi] = *(const f16x8*)(As + (wm * 64 + mi * 16 + fr) * 32 + fq * 8);
#pragma unroll
    for (int ni = 0; ni < 4; ni++)
      bf[ni] = *(const f16x8*)(Ws + (wn * 64 + ni * 16 + fr) * 32 + fq * 8);
#pragma unroll
    for (int mi = 0; mi < 4; mi++)
#pragma unroll
      for (int ni = 0; ni < 4; ni++)
        acc[mi][ni] = __builtin_amdgcn_mfma_f32_16x16x32_f16(af[mi], bf[ni],
                                                             acc[mi][ni], 0, 0, 0);
  }
  __syncthreads();

  if (C32) {
#pragma unroll
    for (int mi = 0; mi < 4; mi++)
#pragma unroll
      for (int ni = 0; ni < 4; ni++)
#pragma unroll
        for (int j = 0; j < 4; j++) {
          float v = acc[mi][ni][j] + bv[ni];
          if (act == 1) v = (v > 0.f) ? v : 0.01f * v;
          C32[(size_t)(bm + wm * 64 + mi * 16 + fq * 4 + j) * HD +
              bn + wn * 64 + ni * 16 + fr] = v;
        }
  } else {
#pragma unroll
    for (int mi = 0; mi < 4; mi++)
#pragma unroll
      for (int ni = 0; ni < 4; ni++)
#pragma unroll
        for (int j = 0; j < 4; j++) {
          float v = acc[mi][ni][j] + bv[ni];
          if (act == 1) v = (v > 0.f) ? v : 0.01f * v;
          EP[(wm * 64 + mi * 16 + fq * 4 + j) * 136 + wn * 64 + ni * 16 + fr] =
              (_Float16)v;
        }
    __syncthreads();
#pragma unroll
    for (int ps = 0; ps < 8; ps++) {
      const int row = ps * 16 + (tid >> 4);
      const f16x8 v = *(const f16x8*)(EP + row * 136 + (tid & 15) * 8);
      *(f16x8*)&C16[(size_t)(bm + row) * HD + bn + (tid & 15) * 8] = v;
    }
  }
}

// ---------------------------------------------------------------------------
// MGU scan, chunked time-parallel (unchanged structure; fp16 xf/xh/z +
// next-step prefetch of xf/xh and the reset flag).
// ---------------------------------------------------------------------------
__global__ __launch_bounds__(512, 2) void scan_mgu(
    const _Float16* __restrict__ xf, const _Float16* __restrict__ xh,
    const void* __restrict__ startp, const int* __restrict__ modep,
    const float* __restrict__ h0l,
    const float* __restrict__ Ufp, const float* __restrict__ Uhp,
    _Float16* __restrict__ z, float* __restrict__ hfin) {
  const int tid  = threadIdx.x;
  const int wave = tid >> 6;      // 0..7
  const int lane = tid & 63;
  const int bcol = lane & 15;     // MFMA col = batch (real < 8)
  const int krow = lane >> 4;     // 0..3
  const int mode = *modep;
  const int t0   = blockIdx.x * CHUNK;
  const int tend = t0 + CHUNK;

  __shared__ __align__(16) float    h32[16][260];
  __shared__ __align__(16) _Float16 h16[16][264];
  __shared__ __align__(16) _Float16 g16[16][264];
  __shared__ int rb[8];

  auto flag = [&](int b, int t) -> int {
    const int idx = b * TT + t;
    if (mode == 1) return ((const int*)startp)[idx] != 0;
    if (mode == 2) return ((const float*)startp)[idx] != 0.0f;
    return ((const uint8_t*)startp)[idx] != 0;
  };

  // Uf/Uh register fragments: wave owns n-tiles {2*wave, 2*wave+1}.
  f16x8 auf[2][8], auh[2][8];
#pragma unroll
  for (int tile = 0; tile < 2; tile++) {
    const int nrow = (wave * 2 + tile) * 16 + bcol;
#pragma unroll
    for (int kc = 0; kc < 8; kc++) {
      const int kb = kc * 32 + krow * 8;
      f16x8 vf, vh;
#pragma unroll
      for (int e = 0; e < 8; e++) {
        vf[e] = (_Float16)Ufp[nrow * HD + kb + e];
        vh[e] = (_Float16)Uhp[nrow * HD + kb + e];
      }
      auf[tile][kc] = vf;
      auh[tile][kc] = vh;
    }
  }

  // Last reset <= t0 per batch.
  if (tid < 8) rb[tid] = -1;
  __syncthreads();
  for (int base = t0; base >= 0; base -= 64) {
    const int sb = tid >> 6;
    const int st = base - (tid & 63);
    if (st >= 0 && rb[sb] < 0 && flag(sb, st)) atomicMax(&rb[sb], st);
    __syncthreads();
    bool all_found = true;
#pragma unroll
    for (int b2 = 0; b2 < 8; b2++) all_found = all_found && (rb[b2] >= 0);
    if (all_found) break;
    __syncthreads();
  }
  int tb = TT;
#pragma unroll
  for (int b2 = 0; b2 < 8; b2++) {
    int r = rb[b2];
    if (r < 0) r = 0;
    tb = min(tb, r);
  }

  // Carry init at t = tb.
  {
    const int b = tid >> 6;
    const int n = (tid & 63) * 4;
    float4 hv = make_float4(0.f, 0.f, 0.f, 0.f);
    if (rb[b] < 0) hv = *(const float4*)&h0l[b * HD + n];
    if (flag(b, tb)) hv = make_float4(0.f, 0.f, 0.f, 0.f);
    *(float4*)&h32[b][n] = hv;
    f16x4 h4;
    h4[0] = (_Float16)hv.x; h4[1] = (_Float16)hv.y;
    h4[2] = (_Float16)hv.z; h4[3] = (_Float16)hv.w;
    *(f16x4*)&h16[b][n] = h4;
  }
  __syncthreads();

  const int bb = (bcol < 8) ? bcol : 7;

  // Prefetch xf/xh + reset flag for first step.
  f16x4 pxf[2], pxh[2];
#pragma unroll
  for (int tile = 0; tile < 2; tile++) {
    const int nb = (wave * 2 + tile) * 16 + krow * 4;
    const size_t ro = ((size_t)bb * TT + tb) * HD + nb;
    pxf[tile] = *(const f16x4*)&xf[ro];
    pxh[tile] = *(const f16x4*)&xh[ro];
  }
  int stn = (tb + 1 < TT) ? flag(bb, tb + 1) : 0;

  for (int t = tb; t < tend; t++) {
    // Consume prefetched C-operands.
    f32x4 cf[2], ch[2];
    float4 hcur[2];
#pragma unroll
    for (int tile = 0; tile < 2; tile++) {
      cf[tile] = (f32x4){(float)pxf[tile][0], (float)pxf[tile][1],
                         (float)pxf[tile][2], (float)pxf[tile][3]};
      ch[tile] = (f32x4){(float)pxh[tile][0], (float)pxh[tile][1],
                         (float)pxh[tile][2], (float)pxh[tile][3]};
    }
    const int st_cur = stn;
    // Issue next step's loads early (latency hidden under this step).
    if (t + 1 < TT) {
#pragma unroll
      for (int tile = 0; tile < 2; tile++) {
        const int nb = (wave * 2 + tile) * 16 + krow * 4;
        const size_t ro = ((size_t)bb * TT + (t + 1)) * HD + nb;
        pxf[tile] = *(const f16x4*)&xf[ro];
        pxh[tile] = *(const f16x4*)&xh[ro];
      }
    }
    stn = (t + 2 < TT) ? flag(bb, t + 2) : 0;

    // matvec1: pre_f = Uf . h + xf
#pragma unroll
    for (int kc = 0; kc < 8; kc++) {
      const f16x8 bvv = *(const f16x8*)&h16[bcol][kc * 32 + krow * 8];
      cf[0] = __builtin_amdgcn_mfma_f32_16x16x32_f16(auf[0][kc], bvv, cf[0], 0, 0, 0);
      cf[1] = __builtin_amdgcn_mfma_f32_16x16x32_f16(auf[1][kc], bvv, cf[1], 0, 0, 0);
    }
    f32x4 fv[2];
#pragma unroll
    for (int tile = 0; tile < 2; tile++) {
      const int nb = (wave * 2 + tile) * 16 + krow * 4;
      const float4 h4 = *(const float4*)&h32[bcol][nb];
      hcur[tile] = h4;
      f16x4 g4;
#pragma unroll
      for (int r = 0; r < 4; r++) {
        const float frr = 1.f / (1.f + __expf(-cf[tile][r]));
        fv[tile][r] = frr;
        g4[r] = (_Float16)(frr * (&h4.x)[r]);
      }
      *(f16x4*)&g16[bcol][nb] = g4;
    }
    __syncthreads();
    // matvec2: pre_h = Uh . (f*h) + xh
#pragma unroll
    for (int kc = 0; kc < 8; kc++) {
      const f16x8 bvv = *(const f16x8*)&g16[bcol][kc * 32 + krow * 8];
      ch[0] = __builtin_amdgcn_mfma_f32_16x16x32_f16(auh[0][kc], bvv, ch[0], 0, 0, 0);
      ch[1] = __builtin_amdgcn_mfma_f32_16x16x32_f16(auh[1][kc], bvv, ch[1], 0, 0, 0);
    }
#pragma unroll
    for (int tile = 0; tile < 2; tile++) {
      const int nb = (wave * 2 + tile) * 16 + krow * 4;
      float4 hn;
      f16x4 zn;
#pragma unroll
      for (int r = 0; r < 4; r++) {
        const float e2 = __expf(2.f * ch[tile][r]);
        const float hh = 1.f - 2.f / (e2 + 1.f);   // tanh
        const float frr = fv[tile][r];
        (&hn.x)[r] = (1.f - frr) * (&hcur[tile].x)[r] + frr * hh;
        zn[r] = (_Float16)(&hn.x)[r];
      }
      if (bcol < 8) {
        if (t >= t0) *(f16x4*)&z[((size_t)bcol * TT + t) * HD + nb] = zn;
        if (t == TT - 1) *(float4*)&hfin[bcol * HD + nb] = hn;
      }
      float4 hst = hn;
      if (st_cur) hst = make_float4(0.f, 0.f, 0.f, 0.f);
      *(float4*)&h32[bcol][nb] = hst;
      f16x4 h4s;
      h4s[0] = (_Float16)hst.x; h4s[1] = (_Float16)hst.y;
      h4s[2] = (_Float16)hst.z; h4s[3] = (_Float16)hst.w;
      *(f16x4*)&h16[bcol][nb] = h4s;
    }
    __syncthreads();
  }
}

// ---------------------------------------------------------------------------
extern "C" void kernel_launch(void* const* d_in, const int* in_sizes, int n_in,
                              void* d_out, int out_size, void* d_ws, size_t ws_size,
                              hipStream_t stream) {
  const float* emb    = (const float*)d_in[0];
  const void*  startp = d_in[1];
  const float* h0     = (const float*)d_in[2];
  const float* min_w  = (const float*)d_in[3];
  const float* min_b  = (const float*)d_in[4];
  const float* mout_w = (const float*)d_in[5];
  const float* mout_b = (const float*)d_in[6];
  const float* Wf_w   = (const float*)d_in[7];
  const float* Wf_b   = (const float*)d_in[8];
  const float* Wh_w   = (const float*)d_in[9];
  const float* Wh_b   = (const float*)d_in[10];
  const float* Uf_w   = (const float*)d_in[11];
  const float* Uh_w   = (const float*)d_in[12];
  const float* ff_w   = (const float*)d_in[13];
  const float* ff_b   = (const float*)d_in[14];

  float* out = (float*)d_out;
  char*  ws  = (char*)d_ws;
  int*   mode = (int*)ws;
  _Float16* w16  = (_Float16*)(ws + 1024);
  _Float16* bufE = (_Float16*)(ws + 1024 + 8 * 65536 * 2);
  _Float16* bufA = bufE + (size_t)RTOT * HD;
  _Float16* bufB = bufA + (size_t)RTOT * HD;
  _Float16* bufC = bufB + (size_t)RTOT * HD;
  float* hfin = out + (size_t)RTOT * HD;
  const size_t WO = (size_t)HD * HD;

  _Float16* w_min = w16;
  _Float16* w_out = w16 + 1 * WO;
  _Float16* w_f0  = w16 + 2 * WO;
  _Float16* w_f1  = w16 + 3 * WO;
  _Float16* w_h0  = w16 + 4 * WO;
  _Float16* w_h1  = w16 + 5 * WO;
  _Float16* w_ff0 = w16 + 6 * WO;
  _Float16* w_ff1 = w16 + 7 * WO;

  detect_start_mode<<<1, 256, 0, stream>>>((const unsigned char*)startp, mode);
  conv_f16<<<RTOT * HD / 2048, 256, 0, stream>>>(emb, bufE, RTOT * HD);
  conv_w8<<<dim3(32, 8), 256, 0, stream>>>(min_w, mout_w, Wf_w, Wf_w + WO,
                                           Wh_w, Wh_w + WO, ff_w, ff_w + WO, w16);

  const dim3 gg(RTOT / 128, HD / 128);
  // x = emb @ min_w^T + min_b
  gemm_h<<<gg, 256, 0, stream>>>(bufE, w_min, min_b, bufA, nullptr, 0);
  // ---- layer 0 ----
  gemm_h<<<gg, 256, 0, stream>>>(bufA, w_f0, Wf_b, bufB, nullptr, 0);
  gemm_h<<<gg, 256, 0, stream>>>(bufA, w_h0, Wh_b, bufC, nullptr, 0);
  scan_mgu<<<NCHUNK, 512, 0, stream>>>(bufB, bufC, startp, mode, h0,
                                       Uf_w, Uh_w, bufA, hfin);
  gemm_h<<<gg, 256, 0, stream>>>(bufA, w_ff0, ff_b, bufB, nullptr, 1);
  // ---- layer 1 ----
  gemm_h<<<gg, 256, 0, stream>>>(bufB, w_f1, Wf_b + HD, bufC, nullptr, 0);
  gemm_h<<<gg, 256, 0, stream>>>(bufB, w_h1, Wh_b + HD, bufA, nullptr, 0);
  scan_mgu<<<NCHUNK, 512, 0, stream>>>(bufC, bufA, startp, mode, h0 + BATCH * HD,
                                       Uf_w + WO, Uh_w + WO, bufB, hfin + BATCH * HD);
  gemm_h<<<gg, 256, 0, stream>>>(bufB, w_ff1, ff_b + HD, bufA, nullptr, 1);
  // out = x @ mout_w^T + mout_b (fp32 direct)
  gemm_h<<<gg, 256, 0, stream>>>(bufA, w_out, mout_b, nullptr, out, 0);
}

// Round 3
// 414.405 us; speedup vs baseline: 3.2686x; 1.4190x over previous
//
#include <hip/hip_runtime.h>
#include <hip/hip_fp16.h>
#include <cstdint>
#include <cstddef>

#define BATCH 8
#define TT 8192
#define HD 256
#define RTOT (BATCH * TT)   // 65536
#define HC 16               // half-chunk length
#define NPAIR (TT / (2 * HC)) // 256 workgroups, each owns 2 half-chunks

typedef __attribute__((ext_vector_type(4))) float    f32x4;
typedef __attribute__((ext_vector_type(8))) _Float16 f16x8;
typedef __attribute__((ext_vector_type(4))) _Float16 f16x4;

typedef __attribute__((address_space(1))) const void gvoid_t;
typedef __attribute__((address_space(3))) void lvoid_t;

__device__ __forceinline__ void gl_lds16(const void* g, void* l) {
  __builtin_amdgcn_global_load_lds((gvoid_t*)g, (lvoid_t*)l, 16, 0, 0);
}

// ---------------------------------------------------------------------------
// Parallel start-flag dtype detection: bad[0]=not-int32, bad[1]=not-f32.
// Examines first 65536 bytes (safe for bool; prefix for int32/f32).
// ---------------------------------------------------------------------------
__global__ void detect_start_par(const unsigned int* __restrict__ s,
                                 int* __restrict__ bad) {
  const unsigned int w = s[blockIdx.x * blockDim.x + threadIdx.x];
  const unsigned int b0 = w & 255u, b1 = (w >> 8) & 255u,
                     b2 = (w >> 16) & 255u, b3 = (w >> 24) & 255u;
  const int bi = (b1 | b2 | b3) != 0;
  const int bf = (b0 != 0) || (b1 != 0) ||
                 (b2 != 0 && b2 != 0x80u) || (b3 != 0 && b3 != 0x3fu);
  if (__any(bi) && (threadIdx.x & 63) == 0) atomicOr(&bad[0], 1);
  if (__any(bf) && (threadIdx.x & 63) == 0) atomicOr(&bad[1], 1);
}

// ---------------------------------------------------------------------------
// f32 -> f16 conversion, vectorized.
// ---------------------------------------------------------------------------
__global__ void conv_f16(const float* __restrict__ in, _Float16* __restrict__ out,
                         const int n) {
  const int i = (blockIdx.x * blockDim.x + threadIdx.x) * 8;
  if (i + 7 >= n) return;
  const float4 a = *(const float4*)&in[i];
  const float4 b = *(const float4*)&in[i + 4];
  f16x8 v;
  v[0] = (_Float16)a.x; v[1] = (_Float16)a.y; v[2] = (_Float16)a.z; v[3] = (_Float16)a.w;
  v[4] = (_Float16)b.x; v[5] = (_Float16)b.y; v[6] = (_Float16)b.z; v[7] = (_Float16)b.w;
  *(f16x8*)&out[i] = v;
}

__global__ void conv_w8(const float* p0, const float* p1, const float* p2,
                        const float* p3, const float* p4, const float* p5,
                        const float* p6, const float* p7,
                        _Float16* __restrict__ out) {
  const int seg = blockIdx.y;
  const float* p;
  switch (seg) {
    case 0: p = p0; break; case 1: p = p1; break;
    case 2: p = p2; break; case 3: p = p3; break;
    case 4: p = p4; break; case 5: p = p5; break;
    case 6: p = p6; break; default: p = p7; break;
  }
  const int i = (blockIdx.x * blockDim.x + threadIdx.x) * 8;
  const float4 a = *(const float4*)&p[i];
  const float4 b = *(const float4*)&p[i + 4];
  f16x8 v;
  v[0] = (_Float16)a.x; v[1] = (_Float16)a.y; v[2] = (_Float16)a.z; v[3] = (_Float16)a.w;
  v[4] = (_Float16)b.x; v[5] = (_Float16)b.y; v[6] = (_Float16)b.z; v[7] = (_Float16)b.w;
  *(f16x8*)&out[(size_t)seg * 65536 + i] = v;
}

// ---------------------------------------------------------------------------
// fp16 MFMA GEMM (single-output), unchanged validated structure from R2.
// ---------------------------------------------------------------------------
__global__ __launch_bounds__(256, 4) void gemm_h(
    const _Float16* __restrict__ A, const _Float16* __restrict__ W,
    const float* __restrict__ bias, _Float16* __restrict__ C16,
    float* __restrict__ C32, const int act) {
  __shared__ __align__(16) char smem[34816];
  _Float16* As = (_Float16*)smem;
  _Float16* Ws = (_Float16*)(smem + 8192);
  _Float16* EP = (_Float16*)smem;

  const int tid  = threadIdx.x;
  const int wave = tid >> 6, lane = tid & 63;
  const int wm = wave >> 1, wn = wave & 1;
  const int bm = blockIdx.x * 128, bn = blockIdx.y * 128;
  const int lrow  = tid >> 2;
  const int lcol8 = (tid & 3) * 8;
  const int fr = lane & 15;
  const int fq = lane >> 4;

  f32x4 acc[4][4];
#pragma unroll
  for (int i = 0; i < 4; i++)
#pragma unroll
    for (int j = 0; j < 4; j++) acc[i][j] = (f32x4){0.f, 0.f, 0.f, 0.f};

  float bv[4];
#pragma unroll
  for (int ni = 0; ni < 4; ni++) bv[ni] = bias[bn + wn * 64 + ni * 16 + fr];

  for (int k0 = 0; k0 < HD; k0 += 32) {
    __syncthreads();
#pragma unroll
    for (int is = 0; is < 2; is++) {
      gl_lds16(&A[(size_t)(bm + is * 64 + lrow) * HD + k0 + lcol8],
               smem + wave * 1024 + is * 4096);
      gl_lds16(&W[(size_t)(bn + is * 64 + lrow) * HD + k0 + lcol8],
               smem + 8192 + wave * 1024 + is * 4096);
    }
    asm volatile("s_waitcnt vmcnt(0)" ::: "memory");
    __syncthreads();
    f16x8 af[4], bf[4];
#pragma unroll
    for (int mi = 0; mi < 4; mi++)
      af[mi] = *(const f16x8*)(As + (wm * 64 + mi * 16 + fr) * 32 + fq * 8);
#pragma unroll
    for (int ni = 0; ni < 4; ni++)
      bf[ni] = *(const f16x8*)(Ws + (wn * 64 + ni * 16 + fr) * 32 + fq * 8);
#pragma unroll
    for (int mi = 0; mi < 4; mi++)
#pragma unroll
      for (int ni = 0; ni < 4; ni++)
        acc[mi][ni] = __builtin_amdgcn_mfma_f32_16x16x32_f16(af[mi], bf[ni],
                                                             acc[mi][ni], 0, 0, 0);
  }
  __syncthreads();

  if (C32) {
#pragma unroll
    for (int mi = 0; mi < 4; mi++)
#pragma unroll
      for (int ni = 0; ni < 4; ni++)
#pragma unroll
        for (int j = 0; j < 4; j++) {
          float v = acc[mi][ni][j] + bv[ni];
          if (act == 1) v = (v > 0.f) ? v : 0.01f * v;
          C32[(size_t)(bm + wm * 64 + mi * 16 + fq * 4 + j) * HD +
              bn + wn * 64 + ni * 16 + fr] = v;
        }
  } else {
#pragma unroll
    for (int mi = 0; mi < 4; mi++)
#pragma unroll
      for (int ni = 0; ni < 4; ni++)
#pragma unroll
        for (int j = 0; j < 4; j++) {
          float v = acc[mi][ni][j] + bv[ni];
          if (act == 1) v = (v > 0.f) ? v : 0.01f * v;
          EP[(wm * 64 + mi * 16 + fq * 4 + j) * 136 + wn * 64 + ni * 16 + fr] =
              (_Float16)v;
        }
    __syncthreads();
#pragma unroll
    for (int ps = 0; ps < 8; ps++) {
      const int row = ps * 16 + (tid >> 4);
      const f16x8 v = *(const f16x8*)(EP + row * 136 + (tid & 15) * 8);
      *(f16x8*)&C16[(size_t)(bm + row) * HD + bn + (tid & 15) * 8] = v;
    }
  }
}

// ---------------------------------------------------------------------------
// Dual-output fp16 MFMA GEMM: C1 = A@W1^T+b1, C2 = A@W2^T+b2 (no act).
// A staged once per k-step; two W tiles, two accumulator sets.
// ---------------------------------------------------------------------------
__global__ __launch_bounds__(256, 2) void gemm_dual(
    const _Float16* __restrict__ A,
    const _Float16* __restrict__ W1, const _Float16* __restrict__ W2,
    const float* __restrict__ b1, const float* __restrict__ b2,
    _Float16* __restrict__ C1, _Float16* __restrict__ C2) {
  __shared__ __align__(16) char smem[34816];
  _Float16* As  = (_Float16*)smem;
  _Float16* Ws1 = (_Float16*)(smem + 8192);
  _Float16* Ws2 = (_Float16*)(smem + 16384);
  _Float16* EP  = (_Float16*)smem;

  const int tid  = threadIdx.x;
  const int wave = tid >> 6, lane = tid & 63;
  const int wm = wave >> 1, wn = wave & 1;
  const int bm = blockIdx.x * 128, bn = blockIdx.y * 128;
  const int lrow  = tid >> 2;
  const int lcol8 = (tid & 3) * 8;
  const int fr = lane & 15;
  const int fq = lane >> 4;

  f32x4 acc1[4][4], acc2[4][4];
#pragma unroll
  for (int i = 0; i < 4; i++)
#pragma unroll
    for (int j = 0; j < 4; j++) {
      acc1[i][j] = (f32x4){0.f, 0.f, 0.f, 0.f};
      acc2[i][j] = (f32x4){0.f, 0.f, 0.f, 0.f};
    }

  float bv1[4], bv2[4];
#pragma unroll
  for (int ni = 0; ni < 4; ni++) {
    bv1[ni] = b1[bn + wn * 64 + ni * 16 + fr];
    bv2[ni] = b2[bn + wn * 64 + ni * 16 + fr];
  }

  for (int k0 = 0; k0 < HD; k0 += 32) {
    __syncthreads();
#pragma unroll
    for (int is = 0; is < 2; is++) {
      gl_lds16(&A[(size_t)(bm + is * 64 + lrow) * HD + k0 + lcol8],
               smem + wave * 1024 + is * 4096);
      gl_lds16(&W1[(size_t)(bn + is * 64 + lrow) * HD + k0 + lcol8],
               smem + 8192 + wave * 1024 + is * 4096);
      gl_lds16(&W2[(size_t)(bn + is * 64 + lrow) * HD + k0 + lcol8],
               smem + 16384 + wave * 1024 + is * 4096);
    }
    asm volatile("s_waitcnt vmcnt(0)" ::: "memory");
    __syncthreads();
    f16x8 af[4], bf1[4], bf2[4];
#pragma unroll
    for (int mi = 0; mi < 4; mi++)
      af[mi] = *(const f16x8*)(As + (wm * 64 + mi * 16 + fr) * 32 + fq * 8);
#pragma unroll
    for (int ni = 0; ni < 4; ni++) {
      bf1[ni] = *(const f16x8*)(Ws1 + (wn * 64 + ni * 16 + fr) * 32 + fq * 8);
      bf2[ni] = *(const f16x8*)(Ws2 + (wn * 64 + ni * 16 + fr) * 32 + fq * 8);
    }
#pragma unroll
    for (int mi = 0; mi < 4; mi++)
#pragma unroll
      for (int ni = 0; ni < 4; ni++) {
        acc1[mi][ni] = __builtin_amdgcn_mfma_f32_16x16x32_f16(af[mi], bf1[ni],
                                                              acc1[mi][ni], 0, 0, 0);
        acc2[mi][ni] = __builtin_amdgcn_mfma_f32_16x16x32_f16(af[mi], bf2[ni],
                                                              acc2[mi][ni], 0, 0, 0);
      }
  }

#pragma unroll
  for (int which = 0; which < 2; which++) {
    __syncthreads();
#pragma unroll
    for (int mi = 0; mi < 4; mi++)
#pragma unroll
      for (int ni = 0; ni < 4; ni++)
#pragma unroll
        for (int j = 0; j < 4; j++) {
          const float v = (which == 0 ? acc1[mi][ni][j] + bv1[ni]
                                      : acc2[mi][ni][j] + bv2[ni]);
          EP[(wm * 64 + mi * 16 + fq * 4 + j) * 136 + wn * 64 + ni * 16 + fr] =
              (_Float16)v;
        }
    __syncthreads();
    _Float16* Cd = (which == 0) ? C1 : C2;
#pragma unroll
    for (int ps = 0; ps < 8; ps++) {
      const int row = ps * 16 + (tid >> 4);
      const f16x8 v = *(const f16x8*)(EP + row * 136 + (tid & 15) * 8);
      *(f16x8*)&Cd[(size_t)(bm + row) * HD + bn + (tid & 15) * 8] = v;
    }
  }
}

// ---------------------------------------------------------------------------
// MGU scan, paired half-chunks: WG bx owns half-chunks {2bx, 2bx+1};
// MFMA cols 0-7 = half-chunk A batches, cols 8-15 = half-chunk B batches
// (per-column time offset +16). Carry h in registers (D-layout);
// h16/g16 in fragment-order LDS (conflict-free reads). Per-column reset
// lookback; per-column carry fold keeps everything exact.
// ---------------------------------------------------------------------------
__global__ __launch_bounds__(512) void scan_mgu(
    const _Float16* __restrict__ xf, const _Float16* __restrict__ xh,
    const void* __restrict__ startp, const int* __restrict__ badf,
    const float* __restrict__ h0l,
    const float* __restrict__ Ufp, const float* __restrict__ Uhp,
    _Float16* __restrict__ z, float* __restrict__ hfin) {
  const int tid  = threadIdx.x;
  const int wave = tid >> 6;
  const int lane = tid & 63;
  const int fr   = lane & 15;      // MFMA col / frag row
  const int fq   = lane >> 4;      // 0..3
  const int col  = fr;
  const int b    = col & 7;
  const int grp  = col >> 3;       // 0 = half-chunk A, 1 = B
  const int t0c  = blockIdx.x * 32 + grp * 16;
  const int mode = (!badf[0]) ? 1 : (!badf[1] ? 2 : 0);

  __shared__ __align__(16) char hbuf[8192];  // frag layout [kc][krow][col][8]
  __shared__ __align__(16) char gbuf[8192];
  __shared__ int rb[16];

  auto flag = [&](int bb, int t) -> int {
    const int idx = bb * TT + t;
    if (mode == 1) return ((const int*)startp)[idx] != 0;
    if (mode == 2) return ((const float*)startp)[idx] != 0.0f;
    return ((const uint8_t*)startp)[idx] != 0;
  };
  auto ldfrag = [&](const char* buf, int kc) -> f16x8 {
    int off = kc * 1024 + fq * 256 + fr * 16;
    off ^= ((off >> 8) & 1) << 4;
    return *(const f16x8*)(buf + off);
  };
  auto stfrag = [&](char* buf, int nb, const float4 v) {
    int off = ((nb >> 5) * 1024) + (((nb >> 3) & 3) * 256) + col * 16 + (nb & 7) * 2;
    off ^= ((off >> 8) & 1) << 4;
    f16x4 p;
    p[0] = (_Float16)v.x; p[1] = (_Float16)v.y;
    p[2] = (_Float16)v.z; p[3] = (_Float16)v.w;
    *(f16x4*)(buf + off) = p;
  };

  // ---- weight fragments (fp32 -> fp16), wave owns n-tiles {2w, 2w+1} ----
  f16x8 auf[2][8], auh[2][8];
#pragma unroll
  for (int tile = 0; tile < 2; tile++) {
    const int nrow = (wave * 2 + tile) * 16 + fr;
#pragma unroll
    for (int kc = 0; kc < 8; kc++) {
      const int kb = kc * 32 + fq * 8;
      const float4 fa = *(const float4*)&Ufp[(size_t)nrow * HD + kb];
      const float4 fb = *(const float4*)&Ufp[(size_t)nrow * HD + kb + 4];
      const float4 ha = *(const float4*)&Uhp[(size_t)nrow * HD + kb];
      const float4 hb = *(const float4*)&Uhp[(size_t)nrow * HD + kb + 4];
      f16x8 vf, vh;
      vf[0] = (_Float16)fa.x; vf[1] = (_Float16)fa.y; vf[2] = (_Float16)fa.z; vf[3] = (_Float16)fa.w;
      vf[4] = (_Float16)fb.x; vf[5] = (_Float16)fb.y; vf[6] = (_Float16)fb.z; vf[7] = (_Float16)fb.w;
      vh[0] = (_Float16)ha.x; vh[1] = (_Float16)ha.y; vh[2] = (_Float16)ha.z; vh[3] = (_Float16)ha.w;
      vh[4] = (_Float16)hb.x; vh[5] = (_Float16)hb.y; vh[6] = (_Float16)hb.z; vh[7] = (_Float16)hb.w;
      auf[tile][kc] = vf;
      auh[tile][kc] = vh;
    }
  }

  // ---- per-column lookback: last reset <= t0c (or -1) ----
  if (tid < 16) rb[tid] = -1;
  __syncthreads();
  {
    const int cg  = tid >> 5;            // 16 groups x 32 threads
    const int l32 = tid & 31;
    const int t0g = blockIdx.x * 32 + (cg >> 3) * 16;
    const int bg  = cg & 7;
    for (int off = 0;; off += 32) {
      const int st = t0g - off - l32;
      if (st >= 0 && rb[cg] < 0 && flag(bg, st)) atomicMax(&rb[cg], st);
      __syncthreads();
      bool done = true;
#pragma unroll
      for (int c = 0; c < 16; c++) {
        const int tc = blockIdx.x * 32 + (c >> 3) * 16;
        if (rb[c] < 0 && tc - off >= 0) done = false;
      }
      if (done) break;
      __syncthreads();
    }
  }
  __syncthreads();

  const int rbc    = rb[col];
  const int startc = max(rbc, 0);
  int Lmax = 0;
#pragma unroll
  for (int c = 0; c < 16; c++) {
    const int tc = blockIdx.x * 32 + (c >> 3) * 16;
    const int s  = max(rb[c], 0);
    Lmax = max(Lmax, tc - s);
  }

  const int nb0 = (wave * 2 + 0) * 16 + fq * 4;
  const int nb1 = (wave * 2 + 1) * 16 + fq * 4;

  // ---- init carry (registers, D-layout) ----
  float4 hinit0 = make_float4(0.f, 0.f, 0.f, 0.f), hinit1 = hinit0;
  if (rbc < 0) {
    hinit0 = *(const float4*)&h0l[b * HD + nb0];
    hinit1 = *(const float4*)&h0l[b * HD + nb1];
  }
  float4 hr0 = hinit0, hr1 = hinit1;
  stfrag(hbuf, nb0, hr0);
  stfrag(hbuf, nb1, hr1);
  __syncthreads();

  // ---- prefetch first step ----
  int t = t0c - Lmax;
  int tcl = min(max(t, 0), TT - 1);
  f16x4 pxf0 = *(const f16x4*)&xf[((size_t)b * TT + tcl) * HD + nb0];
  f16x4 pxf1 = *(const f16x4*)&xf[((size_t)b * TT + tcl) * HD + nb1];
  f16x4 pxh0 = *(const f16x4*)&xh[((size_t)b * TT + tcl) * HD + nb0];
  f16x4 pxh1 = *(const f16x4*)&xh[((size_t)b * TT + tcl) * HD + nb1];

  for (int i = -Lmax; i < HC; i++) {
    t = t0c + i;
    f32x4 cf0 = {(float)pxf0[0], (float)pxf0[1], (float)pxf0[2], (float)pxf0[3]};
    f32x4 cf1 = {(float)pxf1[0], (float)pxf1[1], (float)pxf1[2], (float)pxf1[3]};
    f32x4 ch0 = {(float)pxh0[0], (float)pxh0[1], (float)pxh0[2], (float)pxh0[3]};
    f32x4 ch1 = {(float)pxh1[0], (float)pxh1[1], (float)pxh1[2], (float)pxh1[3]};

    // prefetch next step
    const int tn = min(max(t + 1, 0), TT - 1);
    pxf0 = *(const f16x4*)&xf[((size_t)b * TT + tn) * HD + nb0];
    pxf1 = *(const f16x4*)&xf[((size_t)b * TT + tn) * HD + nb1];
    pxh0 = *(const f16x4*)&xh[((size_t)b * TT + tn) * HD + nb0];
    pxh1 = *(const f16x4*)&xh[((size_t)b * TT + tn) * HD + nb1];

    // carry-fold selector for next step: 2=freeze to init, 1=zero, 0=keep
    int stn = 0;
    if (t + 1 <= startc) stn = 2;
    else if (t + 1 < TT && flag(b, t + 1)) stn = 1;

    // matvec1: pre_f = Uf . h + xf
#pragma unroll
    for (int kc = 0; kc < 8; kc++) {
      const f16x8 bv = ldfrag(hbuf, kc);
      cf0 = __builtin_amdgcn_mfma_f32_16x16x32_f16(auf[0][kc], bv, cf0, 0, 0, 0);
      cf1 = __builtin_amdgcn_mfma_f32_16x16x32_f16(auf[1][kc], bv, cf1, 0, 0, 0);
    }
    // sigmoid, g = f*h
    f32x4 fv0, fv1;
    float4 g0, g1;
#pragma unroll
    for (int r = 0; r < 4; r++) {
      const float f0 = 1.f / (1.f + __expf(-cf0[r]));
      const float f1 = 1.f / (1.f + __expf(-cf1[r]));
      fv0[r] = f0; fv1[r] = f1;
      (&g0.x)[r] = f0 * (&hr0.x)[r];
      (&g1.x)[r] = f1 * (&hr1.x)[r];
    }
    stfrag(gbuf, nb0, g0);
    stfrag(gbuf, nb1, g1);
    __syncthreads();

    // matvec2: pre_h = Uh . (f*h) + xh
#pragma unroll
    for (int kc = 0; kc < 8; kc++) {
      const f16x8 bv = ldfrag(gbuf, kc);
      ch0 = __builtin_amdgcn_mfma_f32_16x16x32_f16(auh[0][kc], bv, ch0, 0, 0, 0);
      ch1 = __builtin_amdgcn_mfma_f32_16x16x32_f16(auh[1][kc], bv, ch1, 0, 0, 0);
    }
    // update
    float4 hn0, hn1;
    f16x4 zn0, zn1;
#pragma unroll
    for (int r = 0; r < 4; r++) {
      const float e0 = __expf(2.f * ch0[r]);
      const float e1 = __expf(2.f * ch1[r]);
      const float hh0 = 1.f - 2.f / (e0 + 1.f);
      const float hh1 = 1.f - 2.f / (e1 + 1.f);
      (&hn0.x)[r] = (1.f - fv0[r]) * (&hr0.x)[r] + fv0[r] * hh0;
      (&hn1.x)[r] = (1.f - fv1[r]) * (&hr1.x)[r] + fv1[r] * hh1;
      zn0[r] = (_Float16)(&hn0.x)[r];
      zn1[r] = (_Float16)(&hn1.x)[r];
    }
    if (i >= 0) {
      *(f16x4*)&z[((size_t)b * TT + t) * HD + nb0] = zn0;
      *(f16x4*)&z[((size_t)b * TT + t) * HD + nb1] = zn1;
    }
    if (t == TT - 1) {
      *(float4*)&hfin[b * HD + nb0] = hn0;
      *(float4*)&hfin[b * HD + nb1] = hn1;
    }
    // fold
    hr0 = (stn == 2) ? hinit0 : (stn == 1 ? make_float4(0.f, 0.f, 0.f, 0.f) : hn0);
    hr1 = (stn == 2) ? hinit1 : (stn == 1 ? make_float4(0.f, 0.f, 0.f, 0.f) : hn1);
    stfrag(hbuf, nb0, hr0);
    stfrag(hbuf, nb1, hr1);
    __syncthreads();
  }
}

// ---------------------------------------------------------------------------
extern "C" void kernel_launch(void* const* d_in, const int* in_sizes, int n_in,
                              void* d_out, int out_size, void* d_ws, size_t ws_size,
                              hipStream_t stream) {
  const float* emb    = (const float*)d_in[0];
  const void*  startp = d_in[1];
  const float* h0     = (const float*)d_in[2];
  const float* min_w  = (const float*)d_in[3];
  const float* min_b  = (const float*)d_in[4];
  const float* mout_w = (const float*)d_in[5];
  const float* mout_b = (const float*)d_in[6];
  const float* Wf_w   = (const float*)d_in[7];
  const float* Wf_b   = (const float*)d_in[8];
  const float* Wh_w   = (const float*)d_in[9];
  const float* Wh_b   = (const float*)d_in[10];
  const float* Uf_w   = (const float*)d_in[11];
  const float* Uh_w   = (const float*)d_in[12];
  const float* ff_w   = (const float*)d_in[13];
  const float* ff_b   = (const float*)d_in[14];

  float* out = (float*)d_out;
  char*  ws  = (char*)d_ws;
  int*   bad = (int*)ws;
  _Float16* w16  = (_Float16*)(ws + 1024);
  _Float16* bufE = (_Float16*)(ws + 1024 + 8 * 65536 * 2);
  _Float16* bufA = bufE + (size_t)RTOT * HD;
  _Float16* bufB = bufA + (size_t)RTOT * HD;
  _Float16* bufC = bufB + (size_t)RTOT * HD;
  float* hfin = out + (size_t)RTOT * HD;
  const size_t WO = (size_t)HD * HD;

  _Float16* w_min = w16;
  _Float16* w_out = w16 + 1 * WO;
  _Float16* w_f0  = w16 + 2 * WO;
  _Float16* w_f1  = w16 + 3 * WO;
  _Float16* w_h0  = w16 + 4 * WO;
  _Float16* w_h1  = w16 + 5 * WO;
  _Float16* w_ff0 = w16 + 6 * WO;
  _Float16* w_ff1 = w16 + 7 * WO;

  hipMemsetAsync(bad, 0, 16, stream);
  detect_start_par<<<64, 256, 0, stream>>>((const unsigned int*)startp, bad);
  conv_f16<<<RTOT * HD / 2048, 256, 0, stream>>>(emb, bufE, RTOT * HD);
  conv_w8<<<dim3(32, 8), 256, 0, stream>>>(min_w, mout_w, Wf_w, Wf_w + WO,
                                           Wh_w, Wh_w + WO, ff_w, ff_w + WO, w16);

  const dim3 gg(RTOT / 128, HD / 128);
  // x = emb @ min_w^T + min_b
  gemm_h<<<gg, 256, 0, stream>>>(bufE, w_min, min_b, bufA, nullptr, 0);
  // ---- layer 0 ----
  gemm_dual<<<gg, 256, 0, stream>>>(bufA, w_f0, w_h0, Wf_b, Wh_b, bufB, bufC);
  scan_mgu<<<NPAIR, 512, 0, stream>>>(bufB, bufC, startp, bad, h0,
                                      Uf_w, Uh_w, bufA, hfin);
  gemm_h<<<gg, 256, 0, stream>>>(bufA, w_ff0, ff_b, bufB, nullptr, 1);
  // ---- layer 1 ----
  gemm_dual<<<gg, 256, 0, stream>>>(bufB, w_f1, w_h1, Wf_b + HD, Wh_b + HD, bufC, bufA);
  scan_mgu<<<NPAIR, 512, 0, stream>>>(bufC, bufA, startp, bad, h0 + BATCH * HD,
                                      Uf_w + WO, Uh_w + WO, bufB, hfin + BATCH * HD);
  gemm_h<<<gg, 256, 0, stream>>>(bufB, w_ff1, ff_b + HD, bufA, nullptr, 1);
  // out = x @ mout_w^T + mout_b (fp32 direct)
  gemm_h<<<gg, 256, 0, stream>>>(bufA, w_out, mout_b, nullptr, out, 0);
}